// Round 1
// baseline (178.400 us; speedup 1.0000x reference)
//
#include <hip/hip_runtime.h>
#include <cstdint>
#include <cstddef>

// ---------------------------------------------------------------------------
// GaussianMixtureAdaptiveProposal: logsumexp_m[ -0.5*||(s_n - x_m)/std||^2
//                                              - 0.5*D*log(2pi) - sum log std ] - log M
// GEMM-shaped (N=8192, M=4096, K=784). Strategy: bf16 MFMA 128x128 tiles
// (m97 structure: global_load_lds width=16, BK=32, 16x16x32 MFMA) with a
// fused flash-style partial logsumexp epilogue; tiny combine kernel.
// ---------------------------------------------------------------------------

#define N_ROWS 8192
#define M_ROWS 4096
#define D_DIM  784
#define KP     800        // K padded to multiple of BK (zeros contribute 0)
#define BK     32
#define LOG2PI 1.8378770664093453f
#define LOGM   8.317766166719343f   // log(4096)

typedef unsigned short u16;
typedef __attribute__((ext_vector_type(8))) __bf16 bf16x8;
typedef __attribute__((ext_vector_type(4))) float  f32x4;
typedef __attribute__((ext_vector_type(4))) u16    u16x4;

// RNE float -> bf16 (bit-level, no header dependency)
__device__ __forceinline__ u16 f2bf(float f) {
    unsigned u = __builtin_bit_cast(unsigned, f);
    unsigned r = (u + 0x7fffu + ((u >> 16) & 1u)) >> 16;
    return (u16)r;
}
__device__ __forceinline__ float bf2f(u16 h) {
    unsigned u = ((unsigned)h) << 16;
    return __builtin_bit_cast(float, u);
}

__device__ __forceinline__ void gld16(const u16* g, u16* l) {
    // async global->LDS, 16B/lane; LDS dest is wave-uniform base + lane*16
    __builtin_amdgcn_global_load_lds(
        (__attribute__((address_space(1))) void*)(void*)g,
        (__attribute__((address_space(3))) void*)l, 16, 0, 0);
}

// --------------------------- k_const: logc ---------------------------------
__global__ __launch_bounds__(256) void k_const(const float* __restrict__ stdv,
                                               float* __restrict__ logc) {
    int t = threadIdx.x;
    float s = 0.f;
    for (int d = t; d < D_DIM; d += 256) s += logf(stdv[d]);
    for (int m = 32; m; m >>= 1) s += __shfl_xor(s, m);
    __shared__ float wsum[4];
    int lane = t & 63, wid = t >> 6;
    if (lane == 0) wsum[wid] = s;
    __syncthreads();
    if (t == 0) logc[0] = -0.5f * (float)D_DIM * LOG2PI - (wsum[0] + wsum[1] + wsum[2] + wsum[3]);
}

// ------------------- k_prep: scale, bf16-round, row norms ------------------
// one block per row; 196 float4 chunks of 784; pad K to 800 with zeros
__global__ __launch_bounds__(256) void k_prep(const float* __restrict__ src,
                                              const float* __restrict__ stdv,
                                              u16* __restrict__ dst,
                                              float* __restrict__ norm) {
    const int row = blockIdx.x;
    const int t = threadIdx.x;
    const float4* s4 = (const float4*)(src + (size_t)row * D_DIM);
    const float4* d4 = (const float4*)stdv;
    u16* drow = dst + (size_t)row * KP;
    float sq = 0.f;
    if (t < 196) {
        float4 s = s4[t];
        float4 d = d4[t];
        u16 b0 = f2bf(s.x / d.x), b1 = f2bf(s.y / d.y);
        u16 b2 = f2bf(s.z / d.z), b3 = f2bf(s.w / d.w);
        float r0 = bf2f(b0), r1 = bf2f(b1), r2 = bf2f(b2), r3 = bf2f(b3);
        sq = r0 * r0 + r1 * r1 + r2 * r2 + r3 * r3;  // norm from ROUNDED values
        u16x4 pack = {b0, b1, b2, b3};
        *(u16x4*)&drow[4 * t] = pack;
    } else if (t < 200) {
        u16x4 z = {0, 0, 0, 0};
        *(u16x4*)&drow[D_DIM + 4 * (t - 196)] = z;
    }
    for (int m = 32; m; m >>= 1) sq += __shfl_xor(sq, m);
    __shared__ float wsum[4];
    int lane = t & 63, wid = t >> 6;
    if (lane == 0) wsum[wid] = sq;
    __syncthreads();
    if (t == 0) norm[row] = wsum[0] + wsum[1] + wsum[2] + wsum[3];
}

// ---------------- k_gemm: 128x128 tile + fused partial LSE -----------------
// grid (32, 64): blockIdx.x = M tile (bCol), blockIdx.y = N tile (bRow)
// partials: pmax/psum [N][32] per (row, col-tile)
__global__ __launch_bounds__(256) void k_gemm(const u16* __restrict__ U,
                                              const u16* __restrict__ V,
                                              const float* __restrict__ unorm,
                                              const float* __restrict__ vnorm,
                                              const float* __restrict__ logcp,
                                              float* __restrict__ pmax,
                                              float* __restrict__ psum) {
    __shared__ u16 uT[128 * BK];   // [row][k], 64B rows, unpadded (global_load_lds)
    __shared__ u16 vT[128 * BK];
    __shared__ float redm[2][128];
    __shared__ float reds[2][128];

    const int tid = threadIdx.x;
    const int lane = tid & 63;
    const int wid = tid >> 6;
    const int waveRow = wid >> 1;   // 0..1 : 64-row half
    const int waveCol = wid & 1;    // 0..1 : 64-col half
    const int bCol = blockIdx.x;    // 0..31
    const int bRow = blockIdx.y;    // 0..63
    const int g  = lane >> 4;       // quad 0..3
    const int rl = lane & 15;

    // staging: 8 chunks of 16 rows x 64B per tile; wave w does chunks {2w,2w+1}
    const int c0 = wid * 2;
    const int srow = c0 * 16 + (lane >> 2);   // row for chunk c0 (c1 = +16)
    const int skc = (lane & 3) * 8;           // 16B sub-chunk within 64B row
    const u16* gu0 = U + (size_t)(bRow * 128 + srow) * KP + skc;
    const u16* gu1 = gu0 + (size_t)16 * KP;
    const u16* gv0 = V + (size_t)(bCol * 128 + srow) * KP + skc;
    const u16* gv1 = gv0 + (size_t)16 * KP;
    u16* lu0 = &uT[c0 * 512];        // wave-uniform LDS bases (chunk*1024B)
    u16* lu1 = &uT[(c0 + 1) * 512];
    u16* lv0 = &vT[c0 * 512];
    u16* lv1 = &vT[(c0 + 1) * 512];

    f32x4 acc[4][4];
#pragma unroll
    for (int i = 0; i < 4; ++i)
#pragma unroll
        for (int j = 0; j < 4; ++j) acc[i][j] = (f32x4){0.f, 0.f, 0.f, 0.f};

    for (int kt = 0; kt < KP / BK; ++kt) {
        const int k0 = kt * BK;
        gld16(gu0 + k0, lu0);
        gld16(gu1 + k0, lu1);
        gld16(gv0 + k0, lv0);
        gld16(gv1 + k0, lv1);
        __syncthreads();   // vmcnt(0) drain + barrier: tiles ready

        bf16x8 a[4], b[4];
#pragma unroll
        for (int i = 0; i < 4; ++i)
            a[i] = *(const bf16x8*)&uT[(waveRow * 64 + i * 16 + rl) * BK + g * 8];
#pragma unroll
        for (int j = 0; j < 4; ++j)
            b[j] = *(const bf16x8*)&vT[(waveCol * 64 + j * 16 + rl) * BK + g * 8];
#pragma unroll
        for (int i = 0; i < 4; ++i)
#pragma unroll
            for (int j = 0; j < 4; ++j)
                acc[i][j] = __builtin_amdgcn_mfma_f32_16x16x32_bf16(a[i], b[j], acc[i][j], 0, 0, 0);

        __syncthreads();   // all reads done before next overwrite
    }

    // ---- epilogue: logp = dot - 0.5*un - 0.5*vn + logc; per-row (max, sumexp)
    // C/D layout: col = lane&15, row-in-16 = g*4 + reg  [verified m89/m91]
    const float logc = logcp[0];
    const int rowbase = bRow * 128 + waveRow * 64 + g * 4;
    float vn[4];
#pragma unroll
    for (int j = 0; j < 4; ++j) vn[j] = vnorm[bCol * 128 + waveCol * 64 + j * 16 + rl];

#pragma unroll
    for (int i = 0; i < 4; ++i) {
        float un[4];
#pragma unroll
        for (int r = 0; r < 4; ++r) un[r] = unorm[rowbase + i * 16 + r];
#pragma unroll
        for (int r = 0; r < 4; ++r) {
            const float rowc = logc - 0.5f * un[r];
            float v0 = acc[i][0][r] - 0.5f * vn[0] + rowc;
            float v1 = acc[i][1][r] - 0.5f * vn[1] + rowc;
            float v2 = acc[i][2][r] - 0.5f * vn[2] + rowc;
            float v3 = acc[i][3][r] - 0.5f * vn[3] + rowc;
            float m = fmaxf(fmaxf(v0, v1), fmaxf(v2, v3));
#pragma unroll
            for (int msk = 1; msk < 16; msk <<= 1) m = fmaxf(m, __shfl_xor(m, msk));
            float s = __expf(v0 - m) + __expf(v1 - m) + __expf(v2 - m) + __expf(v3 - m);
#pragma unroll
            for (int msk = 1; msk < 16; msk <<= 1) s += __shfl_xor(s, msk);
            if (rl == 0) {
                int lr = waveRow * 64 + i * 16 + g * 4 + r;
                redm[waveCol][lr] = m;
                reds[waveCol][lr] = s;
            }
        }
    }
    __syncthreads();
    if (tid < 128) {
        float m0 = redm[0][tid], m1 = redm[1][tid];
        float gm = fmaxf(m0, m1);
        float s = reds[0][tid] * __expf(m0 - gm) + reds[1][tid] * __expf(m1 - gm);
        size_t grow = (size_t)(bRow * 128 + tid);
        pmax[grow * 32 + bCol] = gm;
        psum[grow * 32 + bCol] = s;
    }
}

// --------------------- k_final: combine 32 partials ------------------------
__global__ __launch_bounds__(256) void k_final(const float* __restrict__ pmax,
                                               const float* __restrict__ psum,
                                               float* __restrict__ out) {
    int n = blockIdx.x * 256 + threadIdx.x;
    const float* pm = pmax + (size_t)n * 32;
    const float* ps = psum + (size_t)n * 32;
    float gm = pm[0];
#pragma unroll
    for (int c = 1; c < 32; ++c) gm = fmaxf(gm, pm[c]);
    float S = 0.f;
#pragma unroll
    for (int c = 0; c < 32; ++c) S += ps[c] * __expf(pm[c] - gm);
    out[n] = gm + logf(S) - LOGM;
}

// ---------------------------------------------------------------------------
extern "C" void kernel_launch(void* const* d_in, const int* in_sizes, int n_in,
                              void* d_out, int out_size, void* d_ws, size_t ws_size,
                              hipStream_t stream) {
    const float* samples = (const float*)d_in[0];  // 8192*784
    const float* x       = (const float*)d_in[1];  // 4096*784
    const float* stdv    = (const float*)d_in[2];  // 784
    float* out = (float*)d_out;                    // 8192

    char* ws = (char*)d_ws;
    // layout (all 16B aligned): U bf16 | V bf16 | unorm | vnorm | logc | pmax | psum
    u16*   U     = (u16*)ws;                          // 8192*800*2 = 13,107,200
    u16*   V     = (u16*)(ws + 13107200);             //  4096*800*2 =  6,553,600
    float* unorm = (float*)(ws + 19660800);           //  8192*4
    float* vnorm = (float*)(ws + 19693568);           //  4096*4
    float* logc  = (float*)(ws + 19709952);           //  16 B slot
    float* pmax  = (float*)(ws + 19709968);           //  8192*32*4
    float* psum  = (float*)(ws + 20758544);           //  8192*32*4  (total ~21.8 MB)

    k_const<<<1, 256, 0, stream>>>(stdv, logc);
    k_prep<<<N_ROWS, 256, 0, stream>>>(samples, stdv, U, unorm);
    k_prep<<<M_ROWS, 256, 0, stream>>>(x, stdv, V, vnorm);
    k_gemm<<<dim3(M_ROWS / 128, N_ROWS / 128), 256, 0, stream>>>(U, V, unorm, vnorm, logc, pmax, psum);
    k_final<<<N_ROWS / 256, 256, 0, stream>>>(pmax, psum, out);
}

// Round 2
// 162.887 us; speedup vs baseline: 1.0952x; 1.0952x over previous
//
#include <hip/hip_runtime.h>
#include <cstdint>
#include <cstddef>

// ---------------------------------------------------------------------------
// logsumexp_m[ -0.5*||(s_n - x_m)/std||^2 ] + logc - log M   (N=8192,M=4096,D=784)
// R2: XOR-swizzled LDS staging (kills ds_read_b128 bank conflicts), LDS-based
// epilogue reduction (replaces 128 shuffles/wave), per-row constants deferred
// to k_final, kernels merged 5 -> 3.
// ---------------------------------------------------------------------------

#define N_ROWS 8192
#define M_ROWS 4096
#define D_DIM  784
#define KP     800        // K padded to multiple of BK (zeros contribute 0)
#define BK     32
#define LOG2PI 1.8378770664093453f
#define LOGM   8.317766166719343f   // log(4096)

typedef unsigned short u16;
typedef __attribute__((ext_vector_type(8))) __bf16 bf16x8;
typedef __attribute__((ext_vector_type(4))) float  f32x4;
typedef __attribute__((ext_vector_type(4))) u16    u16x4;

// RNE float -> bf16
__device__ __forceinline__ u16 f2bf(float f) {
    unsigned u = __builtin_bit_cast(unsigned, f);
    unsigned r = (u + 0x7fffu + ((u >> 16) & 1u)) >> 16;
    return (u16)r;
}
__device__ __forceinline__ float bf2f(u16 h) {
    unsigned u = ((unsigned)h) << 16;
    return __builtin_bit_cast(float, u);
}

__device__ __forceinline__ void gld16(const u16* g, u16* l) {
    __builtin_amdgcn_global_load_lds(
        (__attribute__((address_space(1))) void*)(void*)g,
        (__attribute__((address_space(3))) void*)l, 16, 0, 0);
}

// ------------- k_prep: scale, bf16-round, row norms (wave per row) ---------
// grid: (N+M)/4 blocks; block = 4 waves, one row each. Rows >= N_ROWS are x.
__global__ __launch_bounds__(256) void k_prep(const float* __restrict__ samples,
                                              const float* __restrict__ x,
                                              const float* __restrict__ stdv,
                                              u16* __restrict__ dst,
                                              float* __restrict__ norm) {
    const int row = blockIdx.x * 4 + (threadIdx.x >> 6);
    const int lane = threadIdx.x & 63;
    const float* src = (row < N_ROWS) ? samples + (size_t)row * D_DIM
                                      : x + (size_t)(row - N_ROWS) * D_DIM;
    u16* drow = dst + (size_t)row * KP;
    float sq = 0.f;
    for (int c = lane; c < 200; c += 64) {          // 200*4 = 800 = KP
        u16x4 pack = {0, 0, 0, 0};
        if (c < 196) {                              // 196*4 = 784 = D
            float4 s = ((const float4*)src)[c];
            float4 d = ((const float4*)stdv)[c];
            u16 b0 = f2bf(s.x / d.x), b1 = f2bf(s.y / d.y);
            u16 b2 = f2bf(s.z / d.z), b3 = f2bf(s.w / d.w);
            float r0 = bf2f(b0), r1 = bf2f(b1), r2 = bf2f(b2), r3 = bf2f(b3);
            sq += r0 * r0 + r1 * r1 + r2 * r2 + r3 * r3;   // norm of ROUNDED values
            pack = (u16x4){b0, b1, b2, b3};
        }
        *(u16x4*)&drow[4 * c] = pack;
    }
    for (int m = 32; m; m >>= 1) sq += __shfl_xor(sq, m);
    if (lane == 0) norm[row] = sq;
}

// ---------------- k_gemm: 128x128 tile + fused partial LSE -----------------
// LDS swizzle: 16B chunk of (row r, k-chunk c) lives at slot r*4 + (c ^ ((r>>1)&3)).
// Staging permutes the GLOBAL chunk per lane so global_load_lds (dest = base +
// lane*16) produces exactly this layout; 4-lane groups still read one 64B row
// segment -> coalescing unchanged. Frag reads then hit all 8 bank groups evenly.
__global__ __launch_bounds__(256) void k_gemm(const u16* __restrict__ U,
                                              const u16* __restrict__ V,
                                              const float* __restrict__ vnorm,
                                              float* __restrict__ pmax,
                                              float* __restrict__ psum) {
    __shared__ __align__(16) char smem[128 * 33 * 8];   // 33792 B
    u16* uT = (u16*)smem;                 // 128*32 u16 (swizzled)
    u16* vT = uT + 128 * BK;
    float2* part = (float2*)smem;         // [128][33] partials, reuses tile LDS

    const int tid = threadIdx.x;
    const int lane = tid & 63;
    const int wid = tid >> 6;
    const int waveRow = wid >> 1;         // 64-row half
    const int waveCol = wid & 1;          // 64-col half
    const int bCol = blockIdx.x;          // 0..31
    const int bRow = blockIdx.y;          // 0..63
    const int g = lane >> 4, rl = lane & 15;

    // staging: wave wid stages chunks {2wid, 2wid+1} (16 rows x 64B each) of U and V
    const int c0 = wid * 2;
    const int srow = c0 * 16 + (lane >> 2);
    const int gc = (lane & 3) ^ ((lane >> 3) & 3);    // swizzled global chunk
    const u16* gu0 = U + (size_t)(bRow * 128 + srow) * KP + gc * 8;
    const u16* gu1 = gu0 + (size_t)16 * KP;
    const u16* gv0 = V + (size_t)(bCol * 128 + srow) * KP + gc * 8;
    const u16* gv1 = gv0 + (size_t)16 * KP;
    u16* lu0 = &uT[c0 * 512];
    u16* lu1 = &uT[(c0 + 1) * 512];
    u16* lv0 = &vT[c0 * 512];
    u16* lv1 = &vT[(c0 + 1) * 512];

    // hoisted, loop-invariant LDS frag offsets (u16 index)
    const int swz = (rl >> 1) & 3;
    const int aoff = (waveRow * 64 + rl) * BK + (g ^ swz) * 8;
    const int boff = (waveCol * 64 + rl) * BK + (g ^ swz) * 8;

    f32x4 acc[4][4];
#pragma unroll
    for (int i = 0; i < 4; ++i)
#pragma unroll
        for (int j = 0; j < 4; ++j) acc[i][j] = (f32x4){0.f, 0.f, 0.f, 0.f};

    for (int kt = 0; kt < KP / BK; ++kt) {
        const int k0 = kt * BK;
        gld16(gu0 + k0, lu0);
        gld16(gu1 + k0, lu1);
        gld16(gv0 + k0, lv0);
        gld16(gv1 + k0, lv1);
        __syncthreads();   // vmcnt(0) drain + barrier: tiles ready

        bf16x8 a[4], b[4];
#pragma unroll
        for (int i = 0; i < 4; ++i) a[i] = *(const bf16x8*)&uT[aoff + i * 512];
#pragma unroll
        for (int j = 0; j < 4; ++j) b[j] = *(const bf16x8*)&vT[boff + j * 512];
#pragma unroll
        for (int i = 0; i < 4; ++i)
#pragma unroll
            for (int j = 0; j < 4; ++j)
                acc[i][j] = __builtin_amdgcn_mfma_f32_16x16x32_bf16(a[i], b[j], acc[i][j], 0, 0, 0);

        __syncthreads();   // all reads done before next overwrite
    }

    // ---- epilogue: w = dot - 0.5*vn (un & logc deferred to k_final) ----
    // C/D layout: col = lane&15, row-in-16 = g*4 + reg  [m89/m91]
    float vn[4];
#pragma unroll
    for (int j = 0; j < 4; ++j) vn[j] = vnorm[bCol * 128 + waveCol * 64 + j * 16 + rl];

    const int prow0 = waveRow * 64 + g * 4;
    const int pcol = waveCol * 16 + rl;   // which 32-col partial this lane owns
#pragma unroll
    for (int i = 0; i < 4; ++i) {
#pragma unroll
        for (int r = 0; r < 4; ++r) {
            float w0 = acc[i][0][r] - 0.5f * vn[0];
            float w1 = acc[i][1][r] - 0.5f * vn[1];
            float w2 = acc[i][2][r] - 0.5f * vn[2];
            float w3 = acc[i][3][r] - 0.5f * vn[3];
            float m = fmaxf(fmaxf(w0, w1), fmaxf(w2, w3));
            float s = __expf(w0 - m) + __expf(w1 - m) + __expf(w2 - m) + __expf(w3 - m);
            part[(prow0 + i * 16 + r) * 33 + pcol] = make_float2(m, s);
        }
    }
    __syncthreads();
    if (tid < 128) {
        const float2* p = part + tid * 33;
        float m = p[0].x;
#pragma unroll
        for (int c = 1; c < 32; ++c) m = fmaxf(m, p[c].x);
        float s = 0.f;
#pragma unroll
        for (int c = 0; c < 32; ++c) { float2 q = p[c]; s += q.y * __expf(q.x - m); }
        size_t grow = (size_t)(bRow * 128 + tid);
        pmax[grow * 32 + bCol] = m;
        psum[grow * 32 + bCol] = s;
    }
}

// --------------- k_final: combine 32 partials + row constants --------------
__global__ __launch_bounds__(256) void k_final(const float* __restrict__ pmax,
                                               const float* __restrict__ psum,
                                               const float* __restrict__ norm,
                                               const float* __restrict__ stdv,
                                               float* __restrict__ out) {
    __shared__ float wsum[4];
    const int t = threadIdx.x;
    float ls = 0.f;
    for (int d = t; d < D_DIM; d += 256) ls += logf(stdv[d]);
    for (int m = 32; m; m >>= 1) ls += __shfl_xor(ls, m);
    if ((t & 63) == 0) wsum[t >> 6] = ls;
    __syncthreads();
    const float logc = -0.5f * (float)D_DIM * LOG2PI - (wsum[0] + wsum[1] + wsum[2] + wsum[3]);

    const int n = blockIdx.x * 256 + t;
    const float* pm = pmax + (size_t)n * 32;
    const float* ps = psum + (size_t)n * 32;
    float gm = pm[0];
#pragma unroll
    for (int c = 1; c < 32; ++c) gm = fmaxf(gm, pm[c]);
    float S = 0.f;
#pragma unroll
    for (int c = 0; c < 32; ++c) S += ps[c] * __expf(pm[c] - gm);
    out[n] = gm + logf(S) - 0.5f * norm[n] + logc - LOGM;
}

// ---------------------------------------------------------------------------
extern "C" void kernel_launch(void* const* d_in, const int* in_sizes, int n_in,
                              void* d_out, int out_size, void* d_ws, size_t ws_size,
                              hipStream_t stream) {
    const float* samples = (const float*)d_in[0];  // 8192*784
    const float* x       = (const float*)d_in[1];  // 4096*784
    const float* stdv    = (const float*)d_in[2];  // 784
    float* out = (float*)d_out;                    // 8192

    char* ws = (char*)d_ws;
    // U (8192*800 bf16) | V (4096*800 bf16) | norm (12288 f32) | pmax | psum
    u16*   U    = (u16*)ws;                      // 13,107,200 B
    u16*   V    = (u16*)(ws + 13107200);         //  6,553,600 B
    float* norm = (float*)(ws + 19660800);       //     49,152 B
    float* pmax = (float*)(ws + 19709952);       //  1,048,576 B
    float* psum = (float*)(ws + 20758528);       //  1,048,576 B  (total ~21.8 MB)

    k_prep<<<(N_ROWS + M_ROWS) / 4, 256, 0, stream>>>(samples, x, stdv, U, norm);
    k_gemm<<<dim3(M_ROWS / 128, N_ROWS / 128), 256, 0, stream>>>(U, V, norm + N_ROWS, pmax, psum);
    k_final<<<N_ROWS / 256, 256, 0, stream>>>(pmax, psum, norm, stdv, out);
}

// Round 3
// 135.814 us; speedup vs baseline: 1.3136x; 1.1993x over previous
//
#include <hip/hip_runtime.h>
#include <cstdint>
#include <cstddef>

// ---------------------------------------------------------------------------
// logsumexp_m[ -0.5*||(s_n - x_m)/std||^2 ] + logc - log M   (N=8192,M=4096,D=784)
// R3: MX-fp8 path — mfma_scale_f32_16x16x128_f8f6f4 with unit e8m0 scales
// (2x MFMA rate vs bf16, half staging bytes). 16B-granular XOR swizzle
// (slot = chunk ^ (row&7)) keeps LDS reads conflict-free under the
// global_load_lds wave-uniform-dest constraint. k_prep rewritten (rcp hoisted,
// 8 rows/wave, cvt_pk_fp8). Norms computed fp32 from the fp8-ROUNDED vectors
// so sq_dist is the exact distance between rounded vectors.
// ---------------------------------------------------------------------------

#define N_ROWS 8192
#define M_ROWS 4096
#define D_DIM  784
#define KPB    896        // K bytes per row (fp8), padded 784 -> 7*128
#define LOG2PI 1.8378770664093453f
#define LOGM   8.317766166719343f   // log(4096)

typedef unsigned char u8;
typedef __attribute__((ext_vector_type(8))) int   i32x8;
typedef __attribute__((ext_vector_type(4))) float f32x4;

__device__ __forceinline__ void gld16(const u8* g, u8* l) {
    __builtin_amdgcn_global_load_lds(
        (__attribute__((address_space(1))) void*)(void*)g,
        (__attribute__((address_space(3))) void*)l, 16, 0, 0);
}

// ------------- k_prep: scale, fp8-round, row norms (wave x 8 rows) ---------
// grid: 12288/(4 waves * 8 rows) = 384 blocks. Rows >= N_ROWS are x.
__global__ __launch_bounds__(256) void k_prep(const float* __restrict__ samples,
                                              const float* __restrict__ x,
                                              const float* __restrict__ stdv,
                                              u8* __restrict__ dst,
                                              float* __restrict__ norm) {
    const int wid = threadIdx.x >> 6, lane = threadIdx.x & 63;
    const int row0 = blockIdx.x * 32 + wid * 8;

    // hoisted reciprocals for this lane's float4 chunks (c = lane + 64*i)
    float4 rstd[4];
#pragma unroll
    for (int i = 0; i < 4; ++i) {
        int c = lane + 64 * i;
        rstd[i] = make_float4(1.f, 1.f, 1.f, 1.f);
        if (c < 196) {
            float4 d = ((const float4*)stdv)[c];
            rstd[i] = make_float4(1.f / d.x, 1.f / d.y, 1.f / d.z, 1.f / d.w);
        }
    }

    for (int rr = 0; rr < 8; ++rr) {
        const int row = row0 + rr;
        const float* src = (row < N_ROWS) ? samples + (size_t)row * D_DIM
                                          : x + (size_t)(row - N_ROWS) * D_DIM;
        unsigned* drow = (unsigned*)(dst + (size_t)row * KPB);
        float sq = 0.f;
#pragma unroll
        for (int i = 0; i < 4; ++i) {
            const int c = lane + 64 * i;       // u32 chunk (4 fp8 = 4 k-elems)
            if (c < 224) {                     // 224*4 = 896 = KPB
                unsigned p = 0;
                if (c < 196) {                 // 196*4 = 784 = D
                    float4 s = ((const float4*)src)[c];
                    float ux = s.x * rstd[i].x, uy = s.y * rstd[i].y;
                    float uz = s.z * rstd[i].z, uw = s.w * rstd[i].w;
                    p = __builtin_amdgcn_cvt_pk_fp8_f32(ux, uy, 0, false);
                    p = __builtin_amdgcn_cvt_pk_fp8_f32(uz, uw, p, true);
                    float r0 = __builtin_amdgcn_cvt_f32_fp8(p, 0);
                    float r1 = __builtin_amdgcn_cvt_f32_fp8(p, 1);
                    float r2 = __builtin_amdgcn_cvt_f32_fp8(p, 2);
                    float r3 = __builtin_amdgcn_cvt_f32_fp8(p, 3);
                    sq += r0 * r0 + r1 * r1 + r2 * r2 + r3 * r3;  // norm of ROUNDED
                }
                drow[c] = p;
            }
        }
        for (int m = 32; m; m >>= 1) sq += __shfl_xor(sq, m);
        if (lane == 0) norm[row] = sq;
    }
}

// ---------------- k_gemm: 128x128 tile, fp8 MX K=128, fused partial LSE ----
// LDS layout: row-major 128 B rows; 16B chunk c of row r stored at slot c^(r&7).
// Staging permutes the GLOBAL chunk per lane (gc = ch ^ r) so global_load_lds
// (dest = wave-uniform base + lane*16) lands exactly this layout; each 8-lane
// row group still covers one contiguous 128 B segment -> coalescing intact.
// Frag reads (2x ds_read_b128 per operand frag) then hit all 8 bank groups.
__global__ __launch_bounds__(256) void k_gemm(const u8* __restrict__ U,
                                              const u8* __restrict__ V,
                                              const float* __restrict__ vnorm,
                                              float* __restrict__ pmax,
                                              float* __restrict__ psum) {
    __shared__ __align__(16) char smem[128 * 33 * 8];   // 33792 B
    char* uT = smem;                    // 128 rows x 128 B (swizzled)
    char* vT = smem + 16384;
    float2* part = (float2*)smem;       // [128][33] epilogue partials (reuse)

    const int tid = threadIdx.x;
    const int lane = tid & 63;
    const int wid = tid >> 6;
    const int waveRow = wid >> 1;       // 64-row half
    const int waveCol = wid & 1;        // 64-col half
    const int bCol = blockIdx.x;        // 0..31
    const int bRow = blockIdx.y;        // 0..63
    const int g = lane >> 4, rl = lane & 15;

    // staging: wave stages chunks {4w..4w+3} of U and of V (chunk = 8 rows x 128 B)
    const int c0 = wid * 4;
    const int r = lane >> 3;                 // row within chunk (0..7)
    const int gc = (lane & 7) ^ r;           // swizzled global 16B index
    const u8* gu[4]; const u8* gv[4];
    u8* lu[4]; u8* lv[4];
#pragma unroll
    for (int t = 0; t < 4; ++t) {
        const int c = c0 + t;
        gu[t] = U + (size_t)(bRow * 128 + c * 8 + r) * KPB + gc * 16;
        gv[t] = V + (size_t)(bCol * 128 + c * 8 + r) * KPB + gc * 16;
        lu[t] = (u8*)(uT + c * 1024);
        lv[t] = (u8*)(vT + c * 1024);
    }

    // frag read offsets (loop-invariant): frag halves at slots (2g)^key, (2g+1)^key
    const int key = rl & 7;
    const int sA0 = ((2 * g)     ^ key) * 16;
    const int sA1 = ((2 * g + 1) ^ key) * 16;
    const char* aBase = uT + (waveRow * 64 + rl) * 128;
    const char* bBase = vT + (waveCol * 64 + rl) * 128;

    f32x4 acc[4][4];
#pragma unroll
    for (int i = 0; i < 4; ++i)
#pragma unroll
        for (int j = 0; j < 4; ++j) acc[i][j] = (f32x4){0.f, 0.f, 0.f, 0.f};

    for (int kt = 0; kt < KPB / 128; ++kt) {   // 7 iters
        const int k0 = kt * 128;
#pragma unroll
        for (int t = 0; t < 4; ++t) gld16(gu[t] + k0, lu[t]);
#pragma unroll
        for (int t = 0; t < 4; ++t) gld16(gv[t] + k0, lv[t]);
        __syncthreads();   // vmcnt(0) drain + barrier: tiles ready

        i32x8 a[4], b[4];
#pragma unroll
        for (int i = 0; i < 4; ++i) {
            const char* p = aBase + i * 16 * 128;
            int4 lo = *(const int4*)(p + sA0);
            int4 hi = *(const int4*)(p + sA1);
            a[i] = (i32x8){lo.x, lo.y, lo.z, lo.w, hi.x, hi.y, hi.z, hi.w};
        }
#pragma unroll
        for (int j = 0; j < 4; ++j) {
            const char* p = bBase + j * 16 * 128;
            int4 lo = *(const int4*)(p + sA0);
            int4 hi = *(const int4*)(p + sA1);
            b[j] = (i32x8){lo.x, lo.y, lo.z, lo.w, hi.x, hi.y, hi.z, hi.w};
        }
#pragma unroll
        for (int i = 0; i < 4; ++i)
#pragma unroll
            for (int j = 0; j < 4; ++j)
                acc[i][j] = __builtin_amdgcn_mfma_scale_f32_16x16x128_f8f6f4(
                    a[i], b[j], acc[i][j], 0 /*fmtA=fp8*/, 0 /*fmtB=fp8*/,
                    0, 127 /*scaleA=1.0*/, 0, 127 /*scaleB=1.0*/);

        __syncthreads();   // all reads done before next overwrite
    }

    // ---- epilogue: w = dot - 0.5*vn (un & logc deferred to k_final) ----
    // C/D layout (shape-determined): col = lane&15, row-in-16 = g*4 + reg
    float vn[4];
#pragma unroll
    for (int j = 0; j < 4; ++j) vn[j] = vnorm[bCol * 128 + waveCol * 64 + j * 16 + rl];

    const int prow0 = waveRow * 64 + g * 4;
    const int pcol = waveCol * 16 + rl;
#pragma unroll
    for (int i = 0; i < 4; ++i) {
#pragma unroll
        for (int rg = 0; rg < 4; ++rg) {
            float w0 = acc[i][0][rg] - 0.5f * vn[0];
            float w1 = acc[i][1][rg] - 0.5f * vn[1];
            float w2 = acc[i][2][rg] - 0.5f * vn[2];
            float w3 = acc[i][3][rg] - 0.5f * vn[3];
            float m = fmaxf(fmaxf(w0, w1), fmaxf(w2, w3));
            float s = __expf(w0 - m) + __expf(w1 - m) + __expf(w2 - m) + __expf(w3 - m);
            part[(prow0 + i * 16 + rg) * 33 + pcol] = make_float2(m, s);
        }
    }
    __syncthreads();
    if (tid < 128) {
        const float2* p = part + tid * 33;
        float m = p[0].x;
#pragma unroll
        for (int c = 1; c < 32; ++c) m = fmaxf(m, p[c].x);
        float s = 0.f;
#pragma unroll
        for (int c = 0; c < 32; ++c) { float2 q = p[c]; s += q.y * __expf(q.x - m); }
        size_t grow = (size_t)(bRow * 128 + tid);
        pmax[grow * 32 + bCol] = m;
        psum[grow * 32 + bCol] = s;
    }
}

// --------------- k_final: combine 32 partials + row constants --------------
__global__ __launch_bounds__(256) void k_final(const float* __restrict__ pmax,
                                               const float* __restrict__ psum,
                                               const float* __restrict__ norm,
                                               const float* __restrict__ stdv,
                                               float* __restrict__ out) {
    __shared__ float wsum[4];
    const int t = threadIdx.x;
    float ls = 0.f;
    for (int d = t; d < D_DIM; d += 256) ls += logf(stdv[d]);
    for (int m = 32; m; m >>= 1) ls += __shfl_xor(ls, m);
    if ((t & 63) == 0) wsum[t >> 6] = ls;
    __syncthreads();
    const float logc = -0.5f * (float)D_DIM * LOG2PI - (wsum[0] + wsum[1] + wsum[2] + wsum[3]);

    const int n = blockIdx.x * 256 + t;
    const float* pm = pmax + (size_t)n * 32;
    const float* ps = psum + (size_t)n * 32;
    float gm = pm[0];
#pragma unroll
    for (int c = 1; c < 32; ++c) gm = fmaxf(gm, pm[c]);
    float S = 0.f;
#pragma unroll
    for (int c = 0; c < 32; ++c) S += ps[c] * __expf(pm[c] - gm);
    out[n] = gm + logf(S) - 0.5f * norm[n] + logc - LOGM;
}

// ---------------------------------------------------------------------------
extern "C" void kernel_launch(void* const* d_in, const int* in_sizes, int n_in,
                              void* d_out, int out_size, void* d_ws, size_t ws_size,
                              hipStream_t stream) {
    const float* samples = (const float*)d_in[0];  // 8192*784
    const float* x       = (const float*)d_in[1];  // 4096*784
    const float* stdv    = (const float*)d_in[2];  // 784
    float* out = (float*)d_out;                    // 8192

    char* ws = (char*)d_ws;
    // U fp8 (8192*896) | V fp8 (4096*896) | norm (12288 f32) | pmax | psum
    u8*    U    = (u8*)ws;                        //  7,340,032 B
    u8*    V    = (u8*)(ws + 7340032);            //  3,670,016 B
    float* norm = (float*)(ws + 11010048);        //     49,152 B
    float* pmax = (float*)(ws + 11059200);        //  1,048,576 B
    float* psum = (float*)(ws + 12107776);        //  1,048,576 B  (total ~13.2 MB)

    k_prep<<<(N_ROWS + M_ROWS) / 32, 256, 0, stream>>>(samples, x, stdv, U, norm);
    k_gemm<<<dim3(M_ROWS / 128, N_ROWS / 128), 256, 0, stream>>>(U, V, norm + N_ROWS, pmax, psum);
    k_final<<<N_ROWS / 256, 256, 0, stream>>>(pmax, psum, norm, stdv, out);
}

// Round 4
// 124.321 us; speedup vs baseline: 1.4350x; 1.0925x over previous
//
#include <hip/hip_runtime.h>
#include <cstdint>
#include <cstddef>

// ---------------------------------------------------------------------------
// logsumexp_m[ -0.5*||(s_n - x_m)/std||^2 ] + logc - log M   (N=8192,M=4096,D=784)
// R4: software-pipelined double-buffered K-loop (raw s_barrier + manual
// s_waitcnt vmcnt(8) — prefetch next iter's global_load_lds while computing,
// never vmcnt(0) inside the loop). LDS geometry reverted to R2's measured-
// conflict-free 64B-row layout (128B K-rows split into two 64B half-row
// sub-tiles, slot = chunk ^ ((row>>1)&3)). fp8 MX K=128 MFMA as R3.
// ---------------------------------------------------------------------------

#define N_ROWS 8192
#define M_ROWS 4096
#define D_DIM  784
#define KPB    896        // K bytes per row (fp8), padded 784 -> 7*128
#define LOG2PI 1.8378770664093453f
#define LOGM   8.317766166719343f   // log(4096)

typedef unsigned char u8;
typedef __attribute__((ext_vector_type(8))) int   i32x8;
typedef __attribute__((ext_vector_type(4))) float f32x4;

__device__ __forceinline__ void gld16(const u8* g, u8* l) {
    __builtin_amdgcn_global_load_lds(
        (__attribute__((address_space(1))) void*)(void*)g,
        (__attribute__((address_space(3))) void*)l, 16, 0, 0);
}

// ------------- k_prep: scale, fp8-round, row norms (wave x 2 rows) ---------
// grid: 12288/8 = 1536 blocks (4 waves x 2 rows). Rows >= N_ROWS are x.
__global__ __launch_bounds__(256) void k_prep(const float* __restrict__ samples,
                                              const float* __restrict__ x,
                                              const float* __restrict__ stdv,
                                              u8* __restrict__ dst,
                                              float* __restrict__ norm) {
    const int wid = threadIdx.x >> 6, lane = threadIdx.x & 63;
    const int row0 = blockIdx.x * 8 + wid * 2;

    float4 rstd[4];
#pragma unroll
    for (int i = 0; i < 4; ++i) {
        int c = lane + 64 * i;
        rstd[i] = make_float4(1.f, 1.f, 1.f, 1.f);
        if (c < 196) {
            float4 d = ((const float4*)stdv)[c];
            rstd[i] = make_float4(1.f / d.x, 1.f / d.y, 1.f / d.z, 1.f / d.w);
        }
    }

#pragma unroll
    for (int rr = 0; rr < 2; ++rr) {
        const int row = row0 + rr;
        const float* src = (row < N_ROWS) ? samples + (size_t)row * D_DIM
                                          : x + (size_t)(row - N_ROWS) * D_DIM;
        unsigned* drow = (unsigned*)(dst + (size_t)row * KPB);
        float sq = 0.f;
#pragma unroll
        for (int i = 0; i < 4; ++i) {
            const int c = lane + 64 * i;       // u32 chunk (4 fp8)
            if (c < 224) {                     // 224*4 = 896 = KPB
                unsigned p = 0;
                if (c < 196) {                 // 196*4 = 784 = D
                    float4 s = ((const float4*)src)[c];
                    float ux = s.x * rstd[i].x, uy = s.y * rstd[i].y;
                    float uz = s.z * rstd[i].z, uw = s.w * rstd[i].w;
                    p = __builtin_amdgcn_cvt_pk_fp8_f32(ux, uy, 0, false);
                    p = __builtin_amdgcn_cvt_pk_fp8_f32(uz, uw, p, true);
                    float r0 = __builtin_amdgcn_cvt_f32_fp8(p, 0);
                    float r1 = __builtin_amdgcn_cvt_f32_fp8(p, 1);
                    float r2 = __builtin_amdgcn_cvt_f32_fp8(p, 2);
                    float r3 = __builtin_amdgcn_cvt_f32_fp8(p, 3);
                    sq += r0 * r0 + r1 * r1 + r2 * r2 + r3 * r3;  // norm of ROUNDED
                }
                drow[c] = p;
            }
        }
        for (int m = 32; m; m >>= 1) sq += __shfl_xor(sq, m);
        if (lane == 0) norm[row] = sq;
    }
}

// ---------------- k_gemm: 128x128 tile, fp8 MX K=128, pipelined ------------
// LDS per buffer (32KB): A sub-tiles [h][row][slot] at h*8192+row*64+slot*16
// (h = 64B K-half), B at +16384. Slot holds global granule slot^((row>>1)&3)
// — R2's measured-conflict-free geometry (granule = (4*row+slot) mod 8
// rotates through all 8 per read octet). Two buffers at 0 / 32768; epilogue
// partials overlay buffer 0 after the loop.
__global__ __launch_bounds__(256) void k_gemm(const u8* __restrict__ U,
                                              const u8* __restrict__ V,
                                              const float* __restrict__ vnorm,
                                              float* __restrict__ pmax,
                                              float* __restrict__ psum) {
    __shared__ __align__(16) char smem[65536];
    float2* part = (float2*)smem;          // [128][33] epilogue partials

    const int tid = threadIdx.x;
    const int lane = tid & 63;
    const int wid = tid >> 6;
    const int waveRow = wid >> 1;          // 64-row half
    const int waveCol = wid & 1;           // 64-col half
    const int bCol = blockIdx.x;           // 0..31
    const int bRow = blockIdx.y;           // 0..63
    const int g = lane >> 4, rl = lane & 15;

    // ---- staging setup: wave stages 4 A-chunks + 4 B-chunks per iter.
    // chunk linear = wid*4+t: h = lin&1, rowGroup rg = lin>>1 (16 rows x 64B).
    const int r16 = lane >> 2, sl = lane & 3;
    const int gc16 = sl ^ ((r16 >> 1) & 3);          // swizzled global granule
    const u8* ga[4]; const u8* gb[4]; int loff[4];
#pragma unroll
    for (int t = 0; t < 4; ++t) {
        const int lin = wid * 4 + t, h = lin & 1, rg = lin >> 1;
        ga[t] = U + (size_t)(bRow * 128 + rg * 16 + r16) * KPB + h * 64 + gc16 * 16;
        gb[t] = V + (size_t)(bCol * 128 + rg * 16 + r16) * KPB + h * 64 + gc16 * 16;
        loff[t] = h * 8192 + rg * 1024;              // wave-uniform LDS offset
    }

    // ---- hoisted frag-read offsets (within a buffer)
    const int key = (rl >> 1) & 3;
    const int hA = (g >> 1) * 8192;
    const int slotLo = (2 * (g & 1)) ^ key;
    const int aoff = hA + (waveRow * 64 + rl) * 64 + slotLo * 16;           // +i*1024
    const int boff = 16384 + hA + (waveCol * 64 + rl) * 64 + slotLo * 16;   // +j*1024

    f32x4 acc[4][4];
#pragma unroll
    for (int i = 0; i < 4; ++i)
#pragma unroll
        for (int j = 0; j < 4; ++j) acc[i][j] = (f32x4){0.f, 0.f, 0.f, 0.f};

    // prologue: stage kt=0 into buffer 0
#pragma unroll
    for (int t = 0; t < 4; ++t) gld16(ga[t], (u8*)(smem + loff[t]));
#pragma unroll
    for (int t = 0; t < 4; ++t) gld16(gb[t], (u8*)(smem + 16384 + loff[t]));

#pragma unroll
    for (int kt = 0; kt < 7; ++kt) {
        if (kt < 6) {   // prefetch kt+1 into the other buffer
            char* nb = smem + ((kt + 1) & 1) * 32768;
            const int k1 = (kt + 1) * 128;
#pragma unroll
            for (int t = 0; t < 4; ++t) gld16(ga[t] + k1, (u8*)(nb + loff[t]));
#pragma unroll
            for (int t = 0; t < 4; ++t) gld16(gb[t] + k1, (u8*)(nb + 16384 + loff[t]));
            __builtin_amdgcn_s_waitcnt(0x0F78);   // vmcnt(8): kt landed, kt+1 in flight
        } else {
            __builtin_amdgcn_s_waitcnt(0x0F70);   // vmcnt(0): last tile landed
        }
        __builtin_amdgcn_s_barrier();             // all waves' buf(kt) ready

        const char* base = smem + (kt & 1) * 32768;
        i32x8 a[4], b[4];
#pragma unroll
        for (int i = 0; i < 4; ++i) {
            int4 L = *(const int4*)(base + (aoff + i * 1024));
            int4 H = *(const int4*)(base + ((aoff + i * 1024) ^ 16));
            a[i] = (i32x8){L.x, L.y, L.z, L.w, H.x, H.y, H.z, H.w};
        }
#pragma unroll
        for (int j = 0; j < 4; ++j) {
            int4 L = *(const int4*)(base + (boff + j * 1024));
            int4 H = *(const int4*)(base + ((boff + j * 1024) ^ 16));
            b[j] = (i32x8){L.x, L.y, L.z, L.w, H.x, H.y, H.z, H.w};
        }
#pragma unroll
        for (int i = 0; i < 4; ++i)
#pragma unroll
            for (int j = 0; j < 4; ++j)
                acc[i][j] = __builtin_amdgcn_mfma_scale_f32_16x16x128_f8f6f4(
                    a[i], b[j], acc[i][j], 0 /*fp8*/, 0 /*fp8*/,
                    0, 127 /*scaleA=1*/, 0, 127 /*scaleB=1*/);

        __builtin_amdgcn_s_barrier();             // readers of buf(kt) done
    }
    __syncthreads();   // full drain before partials overlay buffer 0

    // ---- epilogue: w = dot - 0.5*vn (un & logc deferred to k_final) ----
    // C/D layout (shape-determined): col = lane&15, row-in-16 = g*4 + reg
    float vn[4];
#pragma unroll
    for (int j = 0; j < 4; ++j) vn[j] = vnorm[bCol * 128 + waveCol * 64 + j * 16 + rl];

    const int prow0 = waveRow * 64 + g * 4;
    const int pcol = waveCol * 16 + rl;
#pragma unroll
    for (int i = 0; i < 4; ++i) {
#pragma unroll
        for (int rg = 0; rg < 4; ++rg) {
            float w0 = acc[i][0][rg] - 0.5f * vn[0];
            float w1 = acc[i][1][rg] - 0.5f * vn[1];
            float w2 = acc[i][2][rg] - 0.5f * vn[2];
            float w3 = acc[i][3][rg] - 0.5f * vn[3];
            float m = fmaxf(fmaxf(w0, w1), fmaxf(w2, w3));
            float s = __expf(w0 - m) + __expf(w1 - m) + __expf(w2 - m) + __expf(w3 - m);
            part[(prow0 + i * 16 + rg) * 33 + pcol] = make_float2(m, s);
        }
    }
    __syncthreads();
    if (tid < 128) {
        const float2* p = part + tid * 33;
        float m = p[0].x;
#pragma unroll
        for (int c = 1; c < 32; ++c) m = fmaxf(m, p[c].x);
        float s = 0.f;
#pragma unroll
        for (int c = 0; c < 32; ++c) { float2 q = p[c]; s += q.y * __expf(q.x - m); }
        size_t grow = (size_t)(bRow * 128 + tid);
        pmax[grow * 32 + bCol] = m;
        psum[grow * 32 + bCol] = s;
    }
}

// --------------- k_final: combine 32 partials + row constants --------------
__global__ __launch_bounds__(256) void k_final(const float* __restrict__ pmax,
                                               const float* __restrict__ psum,
                                               const float* __restrict__ norm,
                                               const float* __restrict__ stdv,
                                               float* __restrict__ out) {
    __shared__ float wsum[4];
    const int t = threadIdx.x;
    float ls = 0.f;
    for (int d = t; d < D_DIM; d += 256) ls += logf(stdv[d]);
    for (int m = 32; m; m >>= 1) ls += __shfl_xor(ls, m);
    if ((t & 63) == 0) wsum[t >> 6] = ls;
    __syncthreads();
    const float logc = -0.5f * (float)D_DIM * LOG2PI - (wsum[0] + wsum[1] + wsum[2] + wsum[3]);

    const int n = blockIdx.x * 256 + t;
    const float* pm = pmax + (size_t)n * 32;
    const float* ps = psum + (size_t)n * 32;
    float gm = pm[0];
#pragma unroll
    for (int c = 1; c < 32; ++c) gm = fmaxf(gm, pm[c]);
    float S = 0.f;
#pragma unroll
    for (int c = 0; c < 32; ++c) S += ps[c] * __expf(pm[c] - gm);
    out[n] = gm + logf(S) - 0.5f * norm[n] + logc - LOGM;
}

// ---------------------------------------------------------------------------
extern "C" void kernel_launch(void* const* d_in, const int* in_sizes, int n_in,
                              void* d_out, int out_size, void* d_ws, size_t ws_size,
                              hipStream_t stream) {
    const float* samples = (const float*)d_in[0];  // 8192*784
    const float* x       = (const float*)d_in[1];  // 4096*784
    const float* stdv    = (const float*)d_in[2];  // 784
    float* out = (float*)d_out;                    // 8192

    char* ws = (char*)d_ws;
    // U fp8 (8192*896) | V fp8 (4096*896) | norm (12288 f32) | pmax | psum
    u8*    U    = (u8*)ws;                        //  7,340,032 B
    u8*    V    = (u8*)(ws + 7340032);            //  3,670,016 B
    float* norm = (float*)(ws + 11010048);        //     49,152 B
    float* pmax = (float*)(ws + 11059200);        //  1,048,576 B
    float* psum = (float*)(ws + 12107776);        //  1,048,576 B  (total ~13.2 MB)

    k_prep<<<(N_ROWS + M_ROWS) / 8, 256, 0, stream>>>(samples, x, stdv, U, norm);
    k_gemm<<<dim3(M_ROWS / 128, N_ROWS / 128), 256, 0, stream>>>(U, V, norm + N_ROWS, pmax, psum);
    k_final<<<N_ROWS / 256, 256, 0, stream>>>(pmax, psum, norm, stdv, out);
}